// Round 13
// baseline (345.080 us; speedup 1.0000x reference)
//
#include <hip/hip_runtime.h>

#define RP 16
#define EMB 16
#define NC 40

// Broadcast lane R (0..15, compile-time constant) of each 16-lane DPP row.
#define BCASTF(dst, srci, R) \
    dst = __int_as_float(__builtin_amdgcn_mov_dpp(srci, 0x150 + R, 0xf, 0xf, true));

// ---------------------------------------------------------------------------
// Bucket counts per s and per o. (s_u is sorted, so cnt_s/offs_s describe
// contiguous t-runs; o-buckets need a real permutation.)
__global__ void k_count(const int* __restrict__ s_u, const int* __restrict__ o_u,
                        int* __restrict__ cnt_s, int* __restrict__ cnt_o, int nt) {
    int t = blockIdx.x * blockDim.x + threadIdx.x;
    if (t < nt) {
        atomicAdd(&cnt_s[s_u[t]], 1);
        atomicAdd(&cnt_o[o_u[t]], 1);
    }
}

// ---------------------------------------------------------------------------
// 3-phase hierarchical exclusive scan (2 arrays via blockIdx.y).
__global__ void k_scan_blk(const int* __restrict__ cnt_s, int* __restrict__ offs_s,
                           const int* __restrict__ cnt_o, int* __restrict__ offs_o,
                           int* __restrict__ partials, int n, int nblk) {
    const int* in = blockIdx.y ? cnt_o : cnt_s;
    int* out = blockIdx.y ? offs_o : offs_s;
    int tid = threadIdx.x;
    int i0 = blockIdx.x * 1024 + tid * 4;
    int v[4];
    #pragma unroll
    for (int q = 0; q < 4; ++q) {
        int i = i0 + q;
        v[q] = (i < n) ? in[i] : 0;
    }
    int tsum = v[0] + v[1] + v[2] + v[3];
    int lane = tid & 63, wid = tid >> 6;
    int x = tsum;
    #pragma unroll
    for (int d = 1; d < 64; d <<= 1) {
        int u = __shfl_up(x, d, 64);
        if (lane >= d) x += u;
    }
    __shared__ int wsum[4];
    if (lane == 63) wsum[wid] = x;
    __syncthreads();
    int woff = 0;
    for (int wq = 0; wq < wid; ++wq) woff += wsum[wq];
    int run = woff + x - tsum;
    #pragma unroll
    for (int q = 0; q < 4; ++q) {
        int i = i0 + q;
        if (i < n) out[i] = run;
        run += v[q];
    }
    if (tid == 255) partials[blockIdx.y * nblk + blockIdx.x] = run;
}

__global__ void k_scan_top(int* __restrict__ partials, int nblk) {
    int w = threadIdx.x >> 6;
    int lane = threadIdx.x & 63;
    int carry = 0;
    for (int base = 0; base < nblk; base += 64) {
        int idx = base + lane;
        int v = (idx < nblk) ? partials[w * nblk + idx] : 0;
        int x = v;
        #pragma unroll
        for (int d = 1; d < 64; d <<= 1) {
            int u = __shfl_up(x, d, 64);
            if (lane >= d) x += u;
        }
        if (idx < nblk) partials[w * nblk + idx] = carry + x - v;
        carry += __shfl(x, 63, 64);
    }
}

__global__ void k_scan_add(int* __restrict__ offs_s, int* __restrict__ cur_s,
                           int* __restrict__ offs_o, int* __restrict__ cur_o,
                           const int* __restrict__ partials, int n, int nblk) {
    int* out = blockIdx.y ? offs_o : offs_s;
    int* cur = blockIdx.y ? cur_o : cur_s;
    int add = partials[blockIdx.y * nblk + blockIdx.x];
    int i0 = blockIdx.x * 1024 + threadIdx.x * 4;
    #pragma unroll
    for (int q = 0; q < 4; ++q) {
        int i = i0 + q;
        if (i < n) {
            int vv = out[i] + add;
            out[i] = vv;
            cur[i] = vv;
        }
    }
}

// ---------------------------------------------------------------------------
// Fused: segment-sum over sorted rm_rows -> softmax ->
//   lat_t  : t-order (coalesced) == s-bucket order (s_u sorted!)
//   lat_o  : o-bucket order (cursor scatter), with su_o companion
//   lat0   : k=0 column in t-order (for the global r0 total)
__global__ void k_latents(const float* __restrict__ rel_emb,
                          const int* __restrict__ rows,
                          const int* __restrict__ cols,
                          const float* __restrict__ vals,
                          const int* __restrict__ s_u,
                          const int* __restrict__ o_u,
                          int* __restrict__ cur_o,
                          float* __restrict__ lat_t, float* __restrict__ lat_o,
                          float* __restrict__ lat0, int* __restrict__ su_o,
                          int nm) {
    int i = blockIdx.x * blockDim.x + threadIdx.x;
    int e = i >> 4, k = i & 15;
    if (e >= nm) return;
    int row = rows[e];
    if (e > 0 && rows[e - 1] == row) return;          // not a row leader
    float acc = vals[e] * rel_emb[cols[e] * RP + k];
    while (e + 1 < nm && rows[e + 1] == row) {
        ++e;
        acc += vals[e] * rel_emb[cols[e] * RP + k];
    }
    float m = acc;
    #pragma unroll
    for (int d = 1; d < 16; d <<= 1) m = fmaxf(m, __shfl_xor(m, d, 16));
    float v = expf(acc - m);
    float s = v;
    #pragma unroll
    for (int d = 1; d < 16; d <<= 1) s += __shfl_xor(s, d, 16);
    v = v / s;
    lat_t[(size_t)row * RP + k] = v;                  // coalesced
    int po = 0;
    if (k == 0) {
        int ou = o_u[row];
        po = atomicAdd(&cur_o[ou], 1);
        su_o[po] = s_u[row];
        lat0[row] = v;
    }
    po = __shfl(po, 0, 16);
    lat_o[(size_t)po * RP + k] = v;                   // scattered 64B row
}

// ---------------------------------------------------------------------------
// Global r0 total G = sum_t lat[t,0] -> rowsum[0], colsum[0].
__global__ void k_r0(const float* __restrict__ lat0,
                     float* __restrict__ rowsum, float* __restrict__ colsum,
                     int nt) {
    float acc = 0.f;
    for (int t = blockIdx.x * blockDim.x + threadIdx.x; t < nt;
         t += gridDim.x * blockDim.x)
        acc += lat0[t];
    #pragma unroll
    for (int d = 32; d; d >>= 1) acc += __shfl_down(acc, d, 64);
    __shared__ float sm[4];
    int lane = threadIdx.x & 63, wid = threadIdx.x >> 6;
    if (lane == 0) sm[wid] = acc;
    __syncthreads();
    if (threadIdx.x == 0) {
        float tot = sm[0] + sm[1] + sm[2] + sm[3];
        atomicAdd(&rowsum[0], tot);
        atomicAdd(&colsum[0], tot);
    }
}

// ---------------------------------------------------------------------------
// colsum: per-o latent sums (linear bucket reads); aliased (v*k) atomics.
__global__ void k_latsum(const float* __restrict__ lat_o,
                         const int* __restrict__ offs_o,
                         const int* __restrict__ cnt_o,
                         float* __restrict__ colsum, int n) {
    int i = blockIdx.x * blockDim.x + threadIdx.x;
    int v = i >> 4, k = i & 15;
    if (v >= n) return;
    int beg = offs_o[v], d = cnt_o[v];
    if (d == 0) return;
    float ls = 0.f;
    int j = 0;
    for (; j + 4 <= d; j += 4) {
        float a0 = lat_o[(size_t)(beg + j + 0) * RP + k];
        float a1 = lat_o[(size_t)(beg + j + 1) * RP + k];
        float a2 = lat_o[(size_t)(beg + j + 2) * RP + k];
        float a3 = lat_o[(size_t)(beg + j + 3) * RP + k];
        ls += (a0 + a1) + (a2 + a3);
    }
    for (; j < d; ++j) ls += lat_o[(size_t)(beg + j) * RP + k];
    if (k >= 1) atomicAdd(&colsum[(size_t)v * k], ls);
}

// ---------------------------------------------------------------------------
// Stage 4: per-o accumulation into raw h. Chunk-16 preload + DPP FMA.
__global__ void k_h_acc(const float* __restrict__ lat_o,
                        const int* __restrict__ offs_o,
                        const int* __restrict__ cnt_o,
                        const int* __restrict__ su_o,
                        const float* __restrict__ colsum,
                        const float* __restrict__ w1,
                        float* __restrict__ h, int n) {
    int i = blockIdx.x * blockDim.x + threadIdx.x;
    int o = i >> 4, k = i & 15;
    if (o >= n) return;
    int d = cnt_o[o];
    if (d == 0) return;
    int beg = offs_o[o];
    float W[RP];
    #pragma unroll
    for (int r = 0; r < RP; ++r)
        W[r] = w1[(size_t)(o * r) * EMB + k];
    float rcp_cs = 1.f / colsum[(size_t)o * k];
    for (int j0 = 0; j0 < d; j0 += 16) {
        int su16 = su_o[beg + min(j0 + k, d - 1)];    // lane k: entry j0+k
        float la[16];
        #pragma unroll
        for (int e = 0; e < 16; ++e)
            la[e] = lat_o[(size_t)(beg + min(j0 + e, d - 1)) * RP + k];
        #pragma unroll
        for (int e = 0; e < 16; ++e) {
            if (j0 + e >= d) break;                   // uniform across group
            float ln = la[e] * rcp_cs;
            int ln_i = __float_as_int(ln);
            float acc = 0.f, b;
            #define HACC_STEP(R) BCASTF(b, ln_i, R); acc = fmaf(b, W[R], acc);
            HACC_STEP(0)  HACC_STEP(1)  HACC_STEP(2)  HACC_STEP(3)
            HACC_STEP(4)  HACC_STEP(5)  HACC_STEP(6)  HACC_STEP(7)
            HACC_STEP(8)  HACC_STEP(9)  HACC_STEP(10) HACC_STEP(11)
            HACC_STEP(12) HACC_STEP(13) HACC_STEP(14) HACC_STEP(15)
            #undef HACC_STEP
            int s = __shfl(su16, e, 16);
            atomicAdd(&h[s * EMB + k], acc);
        }
    }
}

// ---------------------------------------------------------------------------
// Stage 5+6: per-s outer-product. M[r] (r>=1) written PLAIN (collision-free
// [s][r-1][k] layout — s*r is injective for fixed r); collisions are summed
// by the reader (k_out divisor gather). rowsum accumulated here (atomic,
// aliased s*k). r==0 contributions reduced into g0 via r0part.
__global__ void k_h2(const float* __restrict__ lat_t,
                     const int* __restrict__ offs_s,
                     const int* __restrict__ cnt_s,
                     const int* __restrict__ o_u,
                     float* __restrict__ rowsum,
                     const float* __restrict__ h,
                     const float* __restrict__ bias1,
                     float* __restrict__ M2,
                     float* __restrict__ r0part, int n) {
    __shared__ float r0acc[EMB];
    if (threadIdx.x < EMB) r0acc[threadIdx.x] = 0.f;
    __syncthreads();
    int i = blockIdx.x * blockDim.x + threadIdx.x;
    int s = i >> 4, k = i & 15;
    float b1k = bias1[k];
    float M[RP];
    #pragma unroll
    for (int r = 0; r < RP; ++r) M[r] = 0.f;
    float rs_acc = 0.f;
    int d = 0;
    if (s < n) {
        int beg = offs_s[s];
        d = cnt_s[s];
        for (int j0 = 0; j0 < d; j0 += 16) {
            int o16 = o_u[beg + min(j0 + k, d - 1)];  // lane k: entry j0+k
            float hv[16], la[16];
            #pragma unroll
            for (int e = 0; e < 16; ++e) {
                int oe = __shfl(o16, e, 16);
                hv[e] = h[(size_t)oe * EMB + k];      // coalesced 64B row
                la[e] = lat_t[(size_t)(beg + min(j0 + e, d - 1)) * RP + k];
            }
            #pragma unroll
            for (int e = 0; e < 16; ++e) {
                if (j0 + e >= d) break;               // uniform across group
                float hvr = fmaxf(hv[e] + b1k, 0.f);
                rs_acc += la[e];
                int lat_i = __float_as_int(la[e]);
                float b;
                #define H2_STEP(R) BCASTF(b, lat_i, R); M[R] = fmaf(b, hvr, M[R]);
                H2_STEP(0)  H2_STEP(1)  H2_STEP(2)  H2_STEP(3)
                H2_STEP(4)  H2_STEP(5)  H2_STEP(6)  H2_STEP(7)
                H2_STEP(8)  H2_STEP(9)  H2_STEP(10) H2_STEP(11)
                H2_STEP(12) H2_STEP(13) H2_STEP(14) H2_STEP(15)
                #undef H2_STEP
            }
        }
    }
    if (s < n) {
        if (d > 0) {
            if (k >= 1) atomicAdd(&rowsum[(size_t)s * k], rs_acc);
            atomicAdd(&r0acc[k], M[0]);
        }
        float* dst = &M2[(size_t)s * 15 * EMB + k];   // zeros when d == 0
        #pragma unroll
        for (int r = 1; r < RP; ++r)
            dst[(size_t)(r - 1) * EMB] = M[r];
    }
    __syncthreads();
    if (threadIdx.x < EMB)
        r0part[(size_t)blockIdx.x * EMB + threadIdx.x] = r0acc[threadIdx.x];
}

// Reduce r0part (nblk x 16) into g0[0:16]. One block of 1024.
__global__ void k_h2r0(const float* __restrict__ r0part,
                       float* __restrict__ g0, int nblk) {
    __shared__ float red[1024];
    int k = threadIdx.x & 15, j0 = threadIdx.x >> 4;   // j0 in [0,64)
    float acc = 0.f;
    for (int j = j0; j < nblk; j += 64)
        acc += r0part[(size_t)j * EMB + k];
    red[j0 * 16 + k] = acc;
    __syncthreads();
    #pragma unroll
    for (int st = 32; st >= 1; st >>= 1) {
        if (j0 < st) red[j0 * 16 + k] += red[(j0 + st) * 16 + k];
        __syncthreads();
    }
    if (threadIdx.x < 16) g0[threadIdx.x] = red[threadIdx.x];
}

// ---------------------------------------------------------------------------
// Stage 7: 16-lane group per node; lane k owns element k. Divisor gather is
// one coalesced 64B row per hit, done ONCE per node; GEMM via DPP broadcast
// of hv[h] against LDS-staged w2; lane k accumulates c = k, k+16, k+32(k<8).
__global__ void k_out(const float* __restrict__ w2,
                      const float* __restrict__ bias2,
                      const float* __restrict__ M2,
                      const float* __restrict__ g0,
                      const float* __restrict__ rowsum,
                      float* __restrict__ out, int n) {
    __shared__ float w2s[RP * EMB * NC];          // 10240 floats = 40 KB
    for (int i = threadIdx.x; i < RP * EMB * NC; i += 256)
        w2s[i] = w2[i];
    __syncthreads();
    int gi = blockIdx.x * blockDim.x + threadIdx.x;
    int node = gi >> 4, k = gi & 15;
    if (node >= n) return;
    int c2 = (k < 8) ? (k + 32) : 39;                 // clamped dummy for k>=8
    float acc0 = bias2[k];
    float acc1 = bias2[k + 16];
    float acc2 = (k < 8) ? bias2[k + 32] : 0.f;
    for (int rq = 0; rq < RP; ++rq) {
        int m = rq * n + node;
        float hv = (m == 0) ? g0[k] : 0.f;
        // divisor gather: hv += sum over r in [1,16) with r|m, m/r<n
        #pragma unroll
        for (int r = 1; r < RP; ++r) {
            if (m % r == 0) {
                int s = m / r;
                if (s < n)
                    hv += M2[((size_t)s * 15 + (r - 1)) * EMB + k];
            }
        }
        float rs = rowsum[m];
        float rcp = (rs != 0.f) ? 1.f / rs : 0.f;
        hv *= rcp;
        int hv_i = __float_as_int(hv);
        const float* wbase = &w2s[rq * EMB * NC];
        float b;
        #define OUT_STEP(H) BCASTF(b, hv_i, H); \
            acc0 = fmaf(b, wbase[H * NC + k], acc0); \
            acc1 = fmaf(b, wbase[H * NC + k + 16], acc1); \
            acc2 = fmaf(b, wbase[H * NC + c2], acc2);
        OUT_STEP(0)  OUT_STEP(1)  OUT_STEP(2)  OUT_STEP(3)
        OUT_STEP(4)  OUT_STEP(5)  OUT_STEP(6)  OUT_STEP(7)
        OUT_STEP(8)  OUT_STEP(9)  OUT_STEP(10) OUT_STEP(11)
        OUT_STEP(12) OUT_STEP(13) OUT_STEP(14) OUT_STEP(15)
        #undef OUT_STEP
    }
    out[node * NC + k] = acc0;
    out[node * NC + k + 16] = acc1;
    if (k < 8) out[node * NC + k + 32] = acc2;
}

// ---------------------------------------------------------------------------
extern "C" void kernel_launch(void* const* d_in, const int* in_sizes, int n_in,
                              void* d_out, int out_size, void* d_ws, size_t ws_size,
                              hipStream_t stream) {
    const float* rel_emb = (const float*)d_in[0];
    const float* w1      = (const float*)d_in[1];
    const float* w2      = (const float*)d_in[2];
    const float* b1      = (const float*)d_in[3];
    const float* b2      = (const float*)d_in[4];
    const int*   rm_rows = (const int*)d_in[5];
    const int*   rm_cols = (const int*)d_in[6];
    const float* rm_vals = (const float*)d_in[7];
    const int*   h_rows  = (const int*)d_in[8];   // [0:nt] = s_u (sorted!)
    const int*   v_cols  = (const int*)d_in[11];  // [0:nt] = o_u

    const int nm = in_sizes[5];
    const int ne = in_sizes[8];
    const int nt = ne / RP;
    const int n  = in_sizes[1] / (RP * EMB);

    const int B = 256;
    const int nblk_h2 = (n * 16 + B - 1) / B;
    const int nblk_sc = (n + 1023) / 1024;

    char* w = (char*)d_ws;
    // --- zeroed region (small) ---
    float* colsum = (float*)w;  w += (size_t)n * RP * 4;
    float* rowsum = (float*)w;  w += (size_t)n * RP * 4;
    float* h      = (float*)w;  w += (size_t)n * EMB * 4;
    int* cnt_s    = (int*)w;    w += (size_t)n * 4;
    int* cnt_o    = (int*)w;    w += (size_t)n * 4;
    size_t zero_bytes = (size_t)(w - (char*)d_ws);
    // --- written-before-read region ---
    float* M2     = (float*)w;  w += (size_t)n * 15 * EMB * 4;   // 48 MB
    float* lat_t  = (float*)w;  w += (size_t)nt * RP * 4;
    float* lat_o  = (float*)w;  w += (size_t)nt * RP * 4;
    float* lat0   = (float*)w;  w += (size_t)nt * 4;
    int* su_o     = (int*)w;    w += (size_t)nt * 4;
    int* offs_s   = (int*)w;    w += (size_t)n * 4;
    int* cur_s    = (int*)w;    w += (size_t)n * 4;
    int* offs_o   = (int*)w;    w += (size_t)n * 4;
    int* cur_o    = (int*)w;    w += (size_t)n * 4;
    float* r0part = (float*)w;  w += (size_t)nblk_h2 * EMB * 4;
    float* g0     = (float*)w;  w += (size_t)EMB * 4;
    int* partials = (int*)w;    w += (size_t)2 * nblk_sc * 4;
    if ((size_t)(w - (char*)d_ws) > ws_size) return;

    hipMemsetAsync(d_ws, 0, zero_bytes, stream);

    k_count<<<dim3((nt + B - 1) / B), dim3(B), 0, stream>>>(
        h_rows, v_cols, cnt_s, cnt_o, nt);
    k_scan_blk<<<dim3(nblk_sc, 2), dim3(B), 0, stream>>>(
        cnt_s, offs_s, cnt_o, offs_o, partials, n, nblk_sc);
    k_scan_top<<<dim3(1), dim3(128), 0, stream>>>(partials, nblk_sc);
    k_scan_add<<<dim3(nblk_sc, 2), dim3(B), 0, stream>>>(
        offs_s, cur_s, offs_o, cur_o, partials, n, nblk_sc);
    k_latents<<<dim3((nm * 16 + B - 1) / B), dim3(B), 0, stream>>>(
        rel_emb, rm_rows, rm_cols, rm_vals, h_rows, v_cols,
        cur_o, lat_t, lat_o, lat0, su_o, nm);
    k_r0<<<dim3(64), dim3(B), 0, stream>>>(lat0, rowsum, colsum, nt);
    k_latsum<<<dim3((n * 16 + B - 1) / B), dim3(B), 0, stream>>>(
        lat_o, offs_o, cnt_o, colsum, n);
    k_h_acc<<<dim3((n * 16 + B - 1) / B), dim3(B), 0, stream>>>(
        lat_o, offs_o, cnt_o, su_o, colsum, w1, h, n);
    k_h2<<<dim3(nblk_h2), dim3(B), 0, stream>>>(
        lat_t, offs_s, cnt_s, v_cols, rowsum, h, b1, M2, r0part, n);
    k_h2r0<<<dim3(1), dim3(1024), 0, stream>>>(r0part, g0, nblk_h2);
    k_out<<<dim3((n * 16 + B - 1) / B), dim3(B), 0, stream>>>(
        w2, b2, M2, g0, rowsum, (float*)d_out, n);
}

// Round 14
// 324.027 us; speedup vs baseline: 1.0650x; 1.0650x over previous
//
#include <hip/hip_runtime.h>

#define RP 16
#define EMB 16
#define NC 40
#define LSTRIP 128

// Broadcast lane R (0..15, compile-time constant) of each 16-lane DPP row.
#define BCASTF(dst, srci, R) \
    dst = __int_as_float(__builtin_amdgcn_mov_dpp(srci, 0x150 + R, 0xf, 0xf, true));

// ---------------------------------------------------------------------------
// Bucket counts per s and per o. (s_u is sorted, so cnt_s/offs_s describe
// contiguous t-runs; o-buckets need a real permutation.)
__global__ void k_count(const int* __restrict__ s_u, const int* __restrict__ o_u,
                        int* __restrict__ cnt_s, int* __restrict__ cnt_o, int nt) {
    int t = blockIdx.x * blockDim.x + threadIdx.x;
    if (t < nt) {
        atomicAdd(&cnt_s[s_u[t]], 1);
        atomicAdd(&cnt_o[o_u[t]], 1);
    }
}

// ---------------------------------------------------------------------------
// 3-phase hierarchical exclusive scan (2 arrays via blockIdx.y).
__global__ void k_scan_blk(const int* __restrict__ cnt_s, int* __restrict__ offs_s,
                           const int* __restrict__ cnt_o, int* __restrict__ offs_o,
                           int* __restrict__ partials, int n, int nblk) {
    const int* in = blockIdx.y ? cnt_o : cnt_s;
    int* out = blockIdx.y ? offs_o : offs_s;
    int tid = threadIdx.x;
    int i0 = blockIdx.x * 1024 + tid * 4;
    int v[4];
    #pragma unroll
    for (int q = 0; q < 4; ++q) {
        int i = i0 + q;
        v[q] = (i < n) ? in[i] : 0;
    }
    int tsum = v[0] + v[1] + v[2] + v[3];
    int lane = tid & 63, wid = tid >> 6;
    int x = tsum;
    #pragma unroll
    for (int d = 1; d < 64; d <<= 1) {
        int u = __shfl_up(x, d, 64);
        if (lane >= d) x += u;
    }
    __shared__ int wsum[4];
    if (lane == 63) wsum[wid] = x;
    __syncthreads();
    int woff = 0;
    for (int wq = 0; wq < wid; ++wq) woff += wsum[wq];
    int run = woff + x - tsum;
    #pragma unroll
    for (int q = 0; q < 4; ++q) {
        int i = i0 + q;
        if (i < n) out[i] = run;
        run += v[q];
    }
    if (tid == 255) partials[blockIdx.y * nblk + blockIdx.x] = run;
}

__global__ void k_scan_top(int* __restrict__ partials, int nblk) {
    int w = threadIdx.x >> 6;
    int lane = threadIdx.x & 63;
    int carry = 0;
    for (int base = 0; base < nblk; base += 64) {
        int idx = base + lane;
        int v = (idx < nblk) ? partials[w * nblk + idx] : 0;
        int x = v;
        #pragma unroll
        for (int d = 1; d < 64; d <<= 1) {
            int u = __shfl_up(x, d, 64);
            if (lane >= d) x += u;
        }
        if (idx < nblk) partials[w * nblk + idx] = carry + x - v;
        carry += __shfl(x, 63, 64);
    }
}

__global__ void k_scan_add(int* __restrict__ offs_s, int* __restrict__ cur_s,
                           int* __restrict__ offs_o, int* __restrict__ cur_o,
                           const int* __restrict__ partials, int n, int nblk) {
    int* out = blockIdx.y ? offs_o : offs_s;
    int* cur = blockIdx.y ? cur_o : cur_s;
    int add = partials[blockIdx.y * nblk + blockIdx.x];
    int i0 = blockIdx.x * 1024 + threadIdx.x * 4;
    #pragma unroll
    for (int q = 0; q < 4; ++q) {
        int i = i0 + q;
        if (i < n) {
            int vv = out[i] + add;
            out[i] = vv;
            cur[i] = vv;
        }
    }
}

// ---------------------------------------------------------------------------
// Fused: segment-sum over sorted rm_rows -> softmax ->
//   lat_t  : t-order (coalesced) == s-bucket order (s_u sorted!)
//   lat_o  : o-bucket order (cursor scatter), with su_o companion
//   lat0   : k=0 column in t-order (for the global r0 total)
__global__ void k_latents(const float* __restrict__ rel_emb,
                          const int* __restrict__ rows,
                          const int* __restrict__ cols,
                          const float* __restrict__ vals,
                          const int* __restrict__ s_u,
                          const int* __restrict__ o_u,
                          int* __restrict__ cur_o,
                          float* __restrict__ lat_t, float* __restrict__ lat_o,
                          float* __restrict__ lat0, int* __restrict__ su_o,
                          int nm) {
    int i = blockIdx.x * blockDim.x + threadIdx.x;
    int e = i >> 4, k = i & 15;
    if (e >= nm) return;
    int row = rows[e];
    if (e > 0 && rows[e - 1] == row) return;          // not a row leader
    float acc = vals[e] * rel_emb[cols[e] * RP + k];
    while (e + 1 < nm && rows[e + 1] == row) {
        ++e;
        acc += vals[e] * rel_emb[cols[e] * RP + k];
    }
    float m = acc;
    #pragma unroll
    for (int d = 1; d < 16; d <<= 1) m = fmaxf(m, __shfl_xor(m, d, 16));
    float v = expf(acc - m);
    float s = v;
    #pragma unroll
    for (int d = 1; d < 16; d <<= 1) s += __shfl_xor(s, d, 16);
    v = v / s;
    lat_t[(size_t)row * RP + k] = v;                  // coalesced
    int po = 0;
    if (k == 0) {
        int ou = o_u[row];
        po = atomicAdd(&cur_o[ou], 1);
        su_o[po] = s_u[row];
        lat0[row] = v;
    }
    po = __shfl(po, 0, 16);
    lat_o[(size_t)po * RP + k] = v;                   // scattered 64B row
}

// ---------------------------------------------------------------------------
// Global r0 total G = sum_t lat[t,0] -> rowsum[0], colsum[0].
__global__ void k_r0(const float* __restrict__ lat0,
                     float* __restrict__ rowsum, float* __restrict__ colsum,
                     int nt) {
    float acc = 0.f;
    for (int t = blockIdx.x * blockDim.x + threadIdx.x; t < nt;
         t += gridDim.x * blockDim.x)
        acc += lat0[t];
    #pragma unroll
    for (int d = 32; d; d >>= 1) acc += __shfl_down(acc, d, 64);
    __shared__ float sm[4];
    int lane = threadIdx.x & 63, wid = threadIdx.x >> 6;
    if (lane == 0) sm[wid] = acc;
    __syncthreads();
    if (threadIdx.x == 0) {
        float tot = sm[0] + sm[1] + sm[2] + sm[3];
        atomicAdd(&rowsum[0], tot);
        atomicAdd(&colsum[0], tot);
    }
}

// ---------------------------------------------------------------------------
// colsum: per-o latent sums (linear bucket reads); aliased (v*k) atomics.
__global__ void k_latsum(const float* __restrict__ lat_o,
                         const int* __restrict__ offs_o,
                         const int* __restrict__ cnt_o,
                         float* __restrict__ colsum, int n) {
    int i = blockIdx.x * blockDim.x + threadIdx.x;
    int v = i >> 4, k = i & 15;
    if (v >= n) return;
    int beg = offs_o[v], d = cnt_o[v];
    if (d == 0) return;
    float ls = 0.f;
    int j = 0;
    for (; j + 4 <= d; j += 4) {
        float a0 = lat_o[(size_t)(beg + j + 0) * RP + k];
        float a1 = lat_o[(size_t)(beg + j + 1) * RP + k];
        float a2 = lat_o[(size_t)(beg + j + 2) * RP + k];
        float a3 = lat_o[(size_t)(beg + j + 3) * RP + k];
        ls += (a0 + a1) + (a2 + a3);
    }
    for (; j < d; ++j) ls += lat_o[(size_t)(beg + j) * RP + k];
    if (k >= 1) atomicAdd(&colsum[(size_t)v * k], ls);
}

// ---------------------------------------------------------------------------
// Stage 4: per-o accumulation into raw h. Chunk-16 preload + DPP FMA.
__global__ void k_h_acc(const float* __restrict__ lat_o,
                        const int* __restrict__ offs_o,
                        const int* __restrict__ cnt_o,
                        const int* __restrict__ su_o,
                        const float* __restrict__ colsum,
                        const float* __restrict__ w1,
                        float* __restrict__ h, int n) {
    int i = blockIdx.x * blockDim.x + threadIdx.x;
    int o = i >> 4, k = i & 15;
    if (o >= n) return;
    int d = cnt_o[o];
    if (d == 0) return;
    int beg = offs_o[o];
    float W[RP];
    #pragma unroll
    for (int r = 0; r < RP; ++r)
        W[r] = w1[(size_t)(o * r) * EMB + k];
    float rcp_cs = 1.f / colsum[(size_t)o * k];
    for (int j0 = 0; j0 < d; j0 += 16) {
        int su16 = su_o[beg + min(j0 + k, d - 1)];    // lane k: entry j0+k
        float la[16];
        #pragma unroll
        for (int e = 0; e < 16; ++e)
            la[e] = lat_o[(size_t)(beg + min(j0 + e, d - 1)) * RP + k];
        #pragma unroll
        for (int e = 0; e < 16; ++e) {
            if (j0 + e >= d) break;                   // uniform across group
            float ln = la[e] * rcp_cs;
            int ln_i = __float_as_int(ln);
            float acc = 0.f, b;
            #define HACC_STEP(R) BCASTF(b, ln_i, R); acc = fmaf(b, W[R], acc);
            HACC_STEP(0)  HACC_STEP(1)  HACC_STEP(2)  HACC_STEP(3)
            HACC_STEP(4)  HACC_STEP(5)  HACC_STEP(6)  HACC_STEP(7)
            HACC_STEP(8)  HACC_STEP(9)  HACC_STEP(10) HACC_STEP(11)
            HACC_STEP(12) HACC_STEP(13) HACC_STEP(14) HACC_STEP(15)
            #undef HACC_STEP
            int s = __shfl(su16, e, 16);
            atomicAdd(&h[s * EMB + k], acc);
        }
    }
}

// ---------------------------------------------------------------------------
// Stage 5+6: per-s outer-product. M[r] (r>=1) written PLAIN (collision-free
// [s][r-1][k] layout — s*r is injective for fixed r); collisions are summed
// by the reader (k_out r-stream deposit). rowsum accumulated here (atomic,
// aliased s*k). r==0 contributions reduced into g0 via r0part.
__global__ void k_h2(const float* __restrict__ lat_t,
                     const int* __restrict__ offs_s,
                     const int* __restrict__ cnt_s,
                     const int* __restrict__ o_u,
                     float* __restrict__ rowsum,
                     const float* __restrict__ h,
                     const float* __restrict__ bias1,
                     float* __restrict__ M2,
                     float* __restrict__ r0part, int n) {
    __shared__ float r0acc[EMB];
    if (threadIdx.x < EMB) r0acc[threadIdx.x] = 0.f;
    __syncthreads();
    int i = blockIdx.x * blockDim.x + threadIdx.x;
    int s = i >> 4, k = i & 15;
    float b1k = bias1[k];
    float M[RP];
    #pragma unroll
    for (int r = 0; r < RP; ++r) M[r] = 0.f;
    float rs_acc = 0.f;
    int d = 0;
    if (s < n) {
        int beg = offs_s[s];
        d = cnt_s[s];
        for (int j0 = 0; j0 < d; j0 += 16) {
            int o16 = o_u[beg + min(j0 + k, d - 1)];  // lane k: entry j0+k
            float hv[16], la[16];
            #pragma unroll
            for (int e = 0; e < 16; ++e) {
                int oe = __shfl(o16, e, 16);
                hv[e] = h[(size_t)oe * EMB + k];      // coalesced 64B row
                la[e] = lat_t[(size_t)(beg + min(j0 + e, d - 1)) * RP + k];
            }
            #pragma unroll
            for (int e = 0; e < 16; ++e) {
                if (j0 + e >= d) break;               // uniform across group
                float hvr = fmaxf(hv[e] + b1k, 0.f);
                rs_acc += la[e];
                int lat_i = __float_as_int(la[e]);
                float b;
                #define H2_STEP(R) BCASTF(b, lat_i, R); M[R] = fmaf(b, hvr, M[R]);
                H2_STEP(0)  H2_STEP(1)  H2_STEP(2)  H2_STEP(3)
                H2_STEP(4)  H2_STEP(5)  H2_STEP(6)  H2_STEP(7)
                H2_STEP(8)  H2_STEP(9)  H2_STEP(10) H2_STEP(11)
                H2_STEP(12) H2_STEP(13) H2_STEP(14) H2_STEP(15)
                #undef H2_STEP
            }
        }
    }
    if (s < n) {
        if (d > 0) {
            if (k >= 1) atomicAdd(&rowsum[(size_t)s * k], rs_acc);
            atomicAdd(&r0acc[k], M[0]);
        }
        float* dst = &M2[(size_t)s * 15 * EMB + k];   // zeros when d == 0
        #pragma unroll
        for (int r = 1; r < RP; ++r)
            dst[(size_t)(r - 1) * EMB] = M[r];
    }
    __syncthreads();
    if (threadIdx.x < EMB)
        r0part[(size_t)blockIdx.x * EMB + threadIdx.x] = r0acc[threadIdx.x];
}

// Reduce r0part (nblk x 16) into g0[0:16]. One block of 1024.
__global__ void k_h2r0(const float* __restrict__ r0part,
                       float* __restrict__ g0, int nblk) {
    __shared__ float red[1024];
    int k = threadIdx.x & 15, j0 = threadIdx.x >> 4;   // j0 in [0,64)
    float acc = 0.f;
    for (int j = j0; j < nblk; j += 64)
        acc += r0part[(size_t)j * EMB + k];
    red[j0 * 16 + k] = acc;
    __syncthreads();
    #pragma unroll
    for (int st = 32; st >= 1; st >>= 1) {
        if (j0 < st) red[j0 * 16 + k] += red[(j0 + st) * 16 + k];
        __syncthreads();
    }
    if (threadIdx.x < 16) g0[threadIdx.x] = red[threadIdx.x];
}

// ---------------------------------------------------------------------------
// Stage 7 fused: block = 128-node strip. Per rq: zero LDS strip -> deposit
// M2 contributions via 15 COALESCED r-streams (s-range contiguous per r) +
// LDS atomicAdd -> normalize by rowsum -> register GEMM vs LDS w2.
// M2 is read exactly once, fully coalesced; only `out` is written to global.
__global__ void k_out(const float* __restrict__ w2,
                      const float* __restrict__ bias2,
                      const float* __restrict__ M2,
                      const float* __restrict__ g0,
                      const float* __restrict__ rowsum,
                      float* __restrict__ out, int n) {
    __shared__ float w2s[RP * EMB * NC];       // 40 KB
    __shared__ float strip[LSTRIP * EMB];      // 8 KB
    __shared__ float rsq[LSTRIP];
    int tid = threadIdx.x;
    for (int i = tid; i < RP * EMB * NC; i += 256)
        w2s[i] = w2[i];
    int v0 = blockIdx.x * LSTRIP;
    int L = min(LSTRIP, n - v0);
    int node_l = tid >> 1;
    int c0 = (tid & 1) * 20;
    float acc[20];
    #pragma unroll
    for (int c = 0; c < 20; ++c) acc[c] = bias2[c0 + c];
    int g = tid >> 4, k = tid & 15;
    for (int rq = 0; rq < RP; ++rq) {
        __syncthreads();                        // protect previous GEMM reads
        for (int i = tid; i < LSTRIP * EMB; i += 256) strip[i] = 0.f;
        if (tid < LSTRIP) {
            float rs = (tid < L) ? rowsum[(size_t)rq * n + v0 + tid] : 0.f;
            rsq[tid] = (rs != 0.f) ? 1.f / rs : 0.f;
        }
        __syncthreads();
        int m0 = rq * n + v0;
        int mhi = m0 + L - 1;
        #pragma unroll
        for (int r = 1; r < RP; ++r) {
            int slo = (m0 + r - 1) / r;
            int shi = min(n - 1, mhi / r);
            for (int s = slo + g; s <= shi; s += 16) {
                float v = M2[((size_t)s * 15 + (r - 1)) * EMB + k];
                atomicAdd(&strip[(s * r - m0) * EMB + k], v);
            }
        }
        __syncthreads();
        if (rq == 0 && v0 == 0 && tid < EMB)
            strip[tid] += g0[tid];
        __syncthreads();
        if (node_l < L) {
            float rcp = rsq[node_l];
            const float* srow = &strip[node_l * EMB];
            const float* wbase = &w2s[rq * EMB * NC];
            #pragma unroll
            for (int hh = 0; hh < EMB; ++hh) {
                float hv = srow[hh] * rcp;
                const float4* wrow = (const float4*)&wbase[hh * NC + c0];
                #pragma unroll
                for (int q5 = 0; q5 < 5; ++q5) {
                    float4 wv = wrow[q5];
                    acc[q5 * 4 + 0] = fmaf(wv.x, hv, acc[q5 * 4 + 0]);
                    acc[q5 * 4 + 1] = fmaf(wv.y, hv, acc[q5 * 4 + 1]);
                    acc[q5 * 4 + 2] = fmaf(wv.z, hv, acc[q5 * 4 + 2]);
                    acc[q5 * 4 + 3] = fmaf(wv.w, hv, acc[q5 * 4 + 3]);
                }
            }
        }
    }
    if (node_l < L) {
        float4* op = (float4*)&out[(size_t)(v0 + node_l) * NC + c0];
        #pragma unroll
        for (int q5 = 0; q5 < 5; ++q5)
            op[q5] = make_float4(acc[q5 * 4], acc[q5 * 4 + 1],
                                 acc[q5 * 4 + 2], acc[q5 * 4 + 3]);
    }
}

// ---------------------------------------------------------------------------
extern "C" void kernel_launch(void* const* d_in, const int* in_sizes, int n_in,
                              void* d_out, int out_size, void* d_ws, size_t ws_size,
                              hipStream_t stream) {
    const float* rel_emb = (const float*)d_in[0];
    const float* w1      = (const float*)d_in[1];
    const float* w2      = (const float*)d_in[2];
    const float* b1      = (const float*)d_in[3];
    const float* b2      = (const float*)d_in[4];
    const int*   rm_rows = (const int*)d_in[5];
    const int*   rm_cols = (const int*)d_in[6];
    const float* rm_vals = (const float*)d_in[7];
    const int*   h_rows  = (const int*)d_in[8];   // [0:nt] = s_u (sorted!)
    const int*   v_cols  = (const int*)d_in[11];  // [0:nt] = o_u

    const int nm = in_sizes[5];
    const int ne = in_sizes[8];
    const int nt = ne / RP;
    const int n  = in_sizes[1] / (RP * EMB);

    const int B = 256;
    const int nblk_h2 = (n * 16 + B - 1) / B;
    const int nblk_sc = (n + 1023) / 1024;

    char* w = (char*)d_ws;
    // --- zeroed region (small) ---
    float* colsum = (float*)w;  w += (size_t)n * RP * 4;
    float* rowsum = (float*)w;  w += (size_t)n * RP * 4;
    float* h      = (float*)w;  w += (size_t)n * EMB * 4;
    int* cnt_s    = (int*)w;    w += (size_t)n * 4;
    int* cnt_o    = (int*)w;    w += (size_t)n * 4;
    size_t zero_bytes = (size_t)(w - (char*)d_ws);
    // --- written-before-read region ---
    float* M2     = (float*)w;  w += (size_t)n * 15 * EMB * 4;   // 48 MB
    float* lat_t  = (float*)w;  w += (size_t)nt * RP * 4;
    float* lat_o  = (float*)w;  w += (size_t)nt * RP * 4;
    float* lat0   = (float*)w;  w += (size_t)nt * 4;
    int* su_o     = (int*)w;    w += (size_t)nt * 4;
    int* offs_s   = (int*)w;    w += (size_t)n * 4;
    int* cur_s    = (int*)w;    w += (size_t)n * 4;
    int* offs_o   = (int*)w;    w += (size_t)n * 4;
    int* cur_o    = (int*)w;    w += (size_t)n * 4;
    float* r0part = (float*)w;  w += (size_t)nblk_h2 * EMB * 4;
    float* g0     = (float*)w;  w += (size_t)EMB * 4;
    int* partials = (int*)w;    w += (size_t)2 * nblk_sc * 4;
    if ((size_t)(w - (char*)d_ws) > ws_size) return;

    hipMemsetAsync(d_ws, 0, zero_bytes, stream);

    k_count<<<dim3((nt + B - 1) / B), dim3(B), 0, stream>>>(
        h_rows, v_cols, cnt_s, cnt_o, nt);
    k_scan_blk<<<dim3(nblk_sc, 2), dim3(B), 0, stream>>>(
        cnt_s, offs_s, cnt_o, offs_o, partials, n, nblk_sc);
    k_scan_top<<<dim3(1), dim3(128), 0, stream>>>(partials, nblk_sc);
    k_scan_add<<<dim3(nblk_sc, 2), dim3(B), 0, stream>>>(
        offs_s, cur_s, offs_o, cur_o, partials, n, nblk_sc);
    k_latents<<<dim3((nm * 16 + B - 1) / B), dim3(B), 0, stream>>>(
        rel_emb, rm_rows, rm_cols, rm_vals, h_rows, v_cols,
        cur_o, lat_t, lat_o, lat0, su_o, nm);
    k_r0<<<dim3(64), dim3(B), 0, stream>>>(lat0, rowsum, colsum, nt);
    k_latsum<<<dim3((n * 16 + B - 1) / B), dim3(B), 0, stream>>>(
        lat_o, offs_o, cnt_o, colsum, n);
    k_h_acc<<<dim3((n * 16 + B - 1) / B), dim3(B), 0, stream>>>(
        lat_o, offs_o, cnt_o, su_o, colsum, w1, h, n);
    k_h2<<<dim3(nblk_h2), dim3(B), 0, stream>>>(
        lat_t, offs_s, cnt_s, v_cols, rowsum, h, b1, M2, r0part, n);
    k_h2r0<<<dim3(1), dim3(1024), 0, stream>>>(r0part, g0, nblk_h2);
    k_out<<<dim3((n + LSTRIP - 1) / LSTRIP), dim3(B), 0, stream>>>(
        w2, b2, M2, g0, rowsum, (float*)d_out, n);
}

// Round 15
// 291.532 us; speedup vs baseline: 1.1837x; 1.1115x over previous
//
#include <hip/hip_runtime.h>

#define RP 16
#define EMB 16
#define NC 40

// Broadcast lane R (0..15, compile-time constant) of each 16-lane DPP row.
#define BCASTF(dst, srci, R) \
    dst = __int_as_float(__builtin_amdgcn_mov_dpp(srci, 0x150 + R, 0xf, 0xf, true));

// ---------------------------------------------------------------------------
// Bucket counts per s and per o.
__global__ void k_count(const int* __restrict__ s_u, const int* __restrict__ o_u,
                        int* __restrict__ cnt_s, int* __restrict__ cnt_o, int nt) {
    int t = blockIdx.x * blockDim.x + threadIdx.x;
    if (t < nt) {
        atomicAdd(&cnt_s[s_u[t]], 1);
        atomicAdd(&cnt_o[o_u[t]], 1);
    }
}

// ---------------------------------------------------------------------------
// 3-phase hierarchical exclusive scan (2 arrays via blockIdx.y).
__global__ void k_scan_blk(const int* __restrict__ cnt_s, int* __restrict__ offs_s,
                           const int* __restrict__ cnt_o, int* __restrict__ offs_o,
                           int* __restrict__ partials, int n, int nblk) {
    const int* in = blockIdx.y ? cnt_o : cnt_s;
    int* out = blockIdx.y ? offs_o : offs_s;
    int tid = threadIdx.x;
    int i0 = blockIdx.x * 1024 + tid * 4;
    int v[4];
    #pragma unroll
    for (int q = 0; q < 4; ++q) {
        int i = i0 + q;
        v[q] = (i < n) ? in[i] : 0;
    }
    int tsum = v[0] + v[1] + v[2] + v[3];
    int lane = tid & 63, wid = tid >> 6;
    int x = tsum;
    #pragma unroll
    for (int d = 1; d < 64; d <<= 1) {
        int u = __shfl_up(x, d, 64);
        if (lane >= d) x += u;
    }
    __shared__ int wsum[4];
    if (lane == 63) wsum[wid] = x;
    __syncthreads();
    int woff = 0;
    for (int wq = 0; wq < wid; ++wq) woff += wsum[wq];
    int run = woff + x - tsum;
    #pragma unroll
    for (int q = 0; q < 4; ++q) {
        int i = i0 + q;
        if (i < n) out[i] = run;
        run += v[q];
    }
    if (tid == 255) partials[blockIdx.y * nblk + blockIdx.x] = run;
}

__global__ void k_scan_top(int* __restrict__ partials, int nblk) {
    int w = threadIdx.x >> 6;
    int lane = threadIdx.x & 63;
    int carry = 0;
    for (int base = 0; base < nblk; base += 64) {
        int idx = base + lane;
        int v = (idx < nblk) ? partials[w * nblk + idx] : 0;
        int x = v;
        #pragma unroll
        for (int d = 1; d < 64; d <<= 1) {
            int u = __shfl_up(x, d, 64);
            if (lane >= d) x += u;
        }
        if (idx < nblk) partials[w * nblk + idx] = carry + x - v;
        carry += __shfl(x, 63, 64);
    }
}

__global__ void k_scan_add(int* __restrict__ offs_s, int* __restrict__ cur_s,
                           int* __restrict__ offs_o, int* __restrict__ cur_o,
                           const int* __restrict__ partials, int n, int nblk) {
    int* out = blockIdx.y ? offs_o : offs_s;
    int* cur = blockIdx.y ? cur_o : cur_s;
    int add = partials[blockIdx.y * nblk + blockIdx.x];
    int i0 = blockIdx.x * 1024 + threadIdx.x * 4;
    #pragma unroll
    for (int q = 0; q < 4; ++q) {
        int i = i0 + q;
        if (i < n) {
            int vv = out[i] + add;
            out[i] = vv;
            cur[i] = vv;
        }
    }
}

// ---------------------------------------------------------------------------
// Fused: segment-sum over sorted rm_rows -> softmax ->
//   lat_t  : t-order (coalesced) == s-bucket order (s_u sorted!)
//   lat_o  : o-bucket order (cursor scatter), with su_o companion
//   lat0   : k=0 column in t-order (for the global r0 total)
__global__ void k_latents(const float* __restrict__ rel_emb,
                          const int* __restrict__ rows,
                          const int* __restrict__ cols,
                          const float* __restrict__ vals,
                          const int* __restrict__ s_u,
                          const int* __restrict__ o_u,
                          int* __restrict__ cur_o,
                          float* __restrict__ lat_t, float* __restrict__ lat_o,
                          float* __restrict__ lat0, int* __restrict__ su_o,
                          int nm) {
    int i = blockIdx.x * blockDim.x + threadIdx.x;
    int e = i >> 4, k = i & 15;
    if (e >= nm) return;
    int row = rows[e];
    if (e > 0 && rows[e - 1] == row) return;          // not a row leader
    float acc = vals[e] * rel_emb[cols[e] * RP + k];
    while (e + 1 < nm && rows[e + 1] == row) {
        ++e;
        acc += vals[e] * rel_emb[cols[e] * RP + k];
    }
    float m = acc;
    #pragma unroll
    for (int d = 1; d < 16; d <<= 1) m = fmaxf(m, __shfl_xor(m, d, 16));
    float v = expf(acc - m);
    float s = v;
    #pragma unroll
    for (int d = 1; d < 16; d <<= 1) s += __shfl_xor(s, d, 16);
    v = v / s;
    lat_t[(size_t)row * RP + k] = v;                  // coalesced
    int po = 0;
    if (k == 0) {
        int ou = o_u[row];
        po = atomicAdd(&cur_o[ou], 1);
        su_o[po] = s_u[row];
        lat0[row] = v;
    }
    po = __shfl(po, 0, 16);
    lat_o[(size_t)po * RP + k] = v;                   // scattered 64B row
}

// ---------------------------------------------------------------------------
// Global r0 total G = sum_t lat[t,0] -> rowsum[0], colsum[0].
__global__ void k_r0(const float* __restrict__ lat0,
                     float* __restrict__ rowsum, float* __restrict__ colsum,
                     int nt) {
    float acc = 0.f;
    for (int t = blockIdx.x * blockDim.x + threadIdx.x; t < nt;
         t += gridDim.x * blockDim.x)
        acc += lat0[t];
    #pragma unroll
    for (int d = 32; d; d >>= 1) acc += __shfl_down(acc, d, 64);
    __shared__ float sm[4];
    int lane = threadIdx.x & 63, wid = threadIdx.x >> 6;
    if (lane == 0) sm[wid] = acc;
    __syncthreads();
    if (threadIdx.x == 0) {
        float tot = sm[0] + sm[1] + sm[2] + sm[3];
        atomicAdd(&rowsum[0], tot);
        atomicAdd(&colsum[0], tot);
    }
}

// ---------------------------------------------------------------------------
// colsum: per-o latent sums (linear bucket reads); aliased (v*k) atomics.
__global__ void k_latsum(const float* __restrict__ lat_o,
                         const int* __restrict__ offs_o,
                         const int* __restrict__ cnt_o,
                         float* __restrict__ colsum, int n) {
    int i = blockIdx.x * blockDim.x + threadIdx.x;
    int v = i >> 4, k = i & 15;
    if (v >= n) return;
    int beg = offs_o[v], d = cnt_o[v];
    if (d == 0) return;
    float ls = 0.f;
    int j = 0;
    for (; j + 4 <= d; j += 4) {
        float a0 = lat_o[(size_t)(beg + j + 0) * RP + k];
        float a1 = lat_o[(size_t)(beg + j + 1) * RP + k];
        float a2 = lat_o[(size_t)(beg + j + 2) * RP + k];
        float a3 = lat_o[(size_t)(beg + j + 3) * RP + k];
        ls += (a0 + a1) + (a2 + a3);
    }
    for (; j < d; ++j) ls += lat_o[(size_t)(beg + j) * RP + k];
    if (k >= 1) atomicAdd(&colsum[(size_t)v * k], ls);
}

// ---------------------------------------------------------------------------
// Stage 4: per-o accumulation into raw h. Chunk-16 preload + DPP FMA.
__global__ void k_h_acc(const float* __restrict__ lat_o,
                        const int* __restrict__ offs_o,
                        const int* __restrict__ cnt_o,
                        const int* __restrict__ su_o,
                        const float* __restrict__ colsum,
                        const float* __restrict__ w1,
                        float* __restrict__ h, int n) {
    int i = blockIdx.x * blockDim.x + threadIdx.x;
    int o = i >> 4, k = i & 15;
    if (o >= n) return;
    int d = cnt_o[o];
    if (d == 0) return;
    int beg = offs_o[o];
    float W[RP];
    #pragma unroll
    for (int r = 0; r < RP; ++r)
        W[r] = w1[(size_t)(o * r) * EMB + k];
    float rcp_cs = 1.f / colsum[(size_t)o * k];
    for (int j0 = 0; j0 < d; j0 += 16) {
        int su16 = su_o[beg + min(j0 + k, d - 1)];    // lane k: entry j0+k
        float la[16];
        #pragma unroll
        for (int e = 0; e < 16; ++e)
            la[e] = lat_o[(size_t)(beg + min(j0 + e, d - 1)) * RP + k];
        #pragma unroll
        for (int e = 0; e < 16; ++e) {
            if (j0 + e >= d) break;                   // uniform across group
            float ln = la[e] * rcp_cs;
            int ln_i = __float_as_int(ln);
            float acc = 0.f, b;
            #define HACC_STEP(R) BCASTF(b, ln_i, R); acc = fmaf(b, W[R], acc);
            HACC_STEP(0)  HACC_STEP(1)  HACC_STEP(2)  HACC_STEP(3)
            HACC_STEP(4)  HACC_STEP(5)  HACC_STEP(6)  HACC_STEP(7)
            HACC_STEP(8)  HACC_STEP(9)  HACC_STEP(10) HACC_STEP(11)
            HACC_STEP(12) HACC_STEP(13) HACC_STEP(14) HACC_STEP(15)
            #undef HACC_STEP
            int s = __shfl(su16, e, 16);
            atomicAdd(&h[s * EMB + k], acc);
        }
    }
}

// ---------------------------------------------------------------------------
// Stage 5+6: per-s outer-product. M[r] (r>=1) written PLAIN (collision-free
// [s][r-1][k] layout — s*r is injective for fixed r); collisions summed by
// k_gather. rowsum accumulated here (atomic, aliased s*k). r==0 -> g0.
__global__ void k_h2(const float* __restrict__ lat_t,
                     const int* __restrict__ offs_s,
                     const int* __restrict__ cnt_s,
                     const int* __restrict__ o_u,
                     float* __restrict__ rowsum,
                     const float* __restrict__ h,
                     const float* __restrict__ bias1,
                     float* __restrict__ M2,
                     float* __restrict__ r0part, int n) {
    __shared__ float r0acc[EMB];
    if (threadIdx.x < EMB) r0acc[threadIdx.x] = 0.f;
    __syncthreads();
    int i = blockIdx.x * blockDim.x + threadIdx.x;
    int s = i >> 4, k = i & 15;
    float b1k = bias1[k];
    float M[RP];
    #pragma unroll
    for (int r = 0; r < RP; ++r) M[r] = 0.f;
    float rs_acc = 0.f;
    int d = 0;
    if (s < n) {
        int beg = offs_s[s];
        d = cnt_s[s];
        for (int j0 = 0; j0 < d; j0 += 16) {
            int o16 = o_u[beg + min(j0 + k, d - 1)];  // lane k: entry j0+k
            float hv[16], la[16];
            #pragma unroll
            for (int e = 0; e < 16; ++e) {
                int oe = __shfl(o16, e, 16);
                hv[e] = h[(size_t)oe * EMB + k];      // coalesced 64B row
                la[e] = lat_t[(size_t)(beg + min(j0 + e, d - 1)) * RP + k];
            }
            #pragma unroll
            for (int e = 0; e < 16; ++e) {
                if (j0 + e >= d) break;               // uniform across group
                float hvr = fmaxf(hv[e] + b1k, 0.f);
                rs_acc += la[e];
                int lat_i = __float_as_int(la[e]);
                float b;
                #define H2_STEP(R) BCASTF(b, lat_i, R); M[R] = fmaf(b, hvr, M[R]);
                H2_STEP(0)  H2_STEP(1)  H2_STEP(2)  H2_STEP(3)
                H2_STEP(4)  H2_STEP(5)  H2_STEP(6)  H2_STEP(7)
                H2_STEP(8)  H2_STEP(9)  H2_STEP(10) H2_STEP(11)
                H2_STEP(12) H2_STEP(13) H2_STEP(14) H2_STEP(15)
                #undef H2_STEP
            }
        }
    }
    if (s < n) {
        if (d > 0) {
            if (k >= 1) atomicAdd(&rowsum[(size_t)s * k], rs_acc);
            atomicAdd(&r0acc[k], M[0]);
        }
        float* dst = &M2[(size_t)s * 15 * EMB + k];   // zeros when d == 0
        #pragma unroll
        for (int r = 1; r < RP; ++r)
            dst[(size_t)(r - 1) * EMB] = M[r];
    }
    __syncthreads();
    if (threadIdx.x < EMB)
        r0part[(size_t)blockIdx.x * EMB + threadIdx.x] = r0acc[threadIdx.x];
}

// Reduce r0part (nblk x 16) into g0[0:16]. One block of 1024.
__global__ void k_h2r0(const float* __restrict__ r0part,
                       float* __restrict__ g0, int nblk) {
    __shared__ float red[1024];
    int k = threadIdx.x & 15, j0 = threadIdx.x >> 4;   // j0 in [0,64)
    float acc = 0.f;
    for (int j = j0; j < nblk; j += 64)
        acc += r0part[(size_t)j * EMB + k];
    red[j0 * 16 + k] = acc;
    __syncthreads();
    #pragma unroll
    for (int st = 32; st >= 1; st >>= 1) {
        if (j0 < st) red[j0 * 16 + k] += red[(j0 + st) * 16 + k];
        __syncthreads();
    }
    if (threadIdx.x < 16) g0[threadIdx.x] = red[threadIdx.x];
}

// ---------------------------------------------------------------------------
// Collision gather: 16-lane group per flat row m; divisor-test r|m, read M2
// rows coalesced (each exactly once across the grid), normalize by rowsum[m],
// write dense h2n. No LDS, no barriers, no atomics; 16n groups.
__global__ void k_gather(const float* __restrict__ M2,
                         const float* __restrict__ g0,
                         const float* __restrict__ rowsum,
                         float* __restrict__ h2n, int n) {
    int gi = blockIdx.x * blockDim.x + threadIdx.x;
    int m = gi >> 4, k = gi & 15;
    if (m >= n * RP) return;
    float hv = (m == 0) ? g0[k] : 0.f;
    #pragma unroll
    for (int r = 1; r < RP; ++r) {
        if (m % r == 0) {
            int s = m / r;
            if (s < n)
                hv += M2[((size_t)s * 15 + (r - 1)) * EMB + k];
        }
    }
    float rs = rowsum[m];
    float rcp = (rs != 0.f) ? 1.f / rs : 0.f;
    h2n[(size_t)m * EMB + k] = hv * rcp;
}

// ---------------------------------------------------------------------------
// Stage 7 (round-8 shape): w2 staged in LDS; thread = (node, 20-col half);
// dense pre-normalized h2n rows, float4 everywhere.
#define CB2 20
__global__ void k_out(const float* __restrict__ w2,
                      const float* __restrict__ bias2,
                      const float* __restrict__ h2n,
                      float* __restrict__ out, int n) {
    __shared__ float w2s[RP * EMB * NC];          // 10240 floats = 40 KB
    for (int i = threadIdx.x; i < RP * EMB * NC; i += 256)
        w2s[i] = w2[i];
    __syncthreads();
    int gi = blockIdx.x * blockDim.x + threadIdx.x;
    int node = gi >> 1;
    int c0 = (gi & 1) * CB2;
    if (node >= n) return;
    float acc[CB2];
    #pragma unroll
    for (int c = 0; c < CB2; ++c) acc[c] = bias2[c0 + c];
    for (int rq = 0; rq < RP; ++rq) {
        const float4* h2row = (const float4*)&h2n[((size_t)rq * n + node) * EMB];
        float4 hv4[4];
        #pragma unroll
        for (int q = 0; q < 4; ++q) hv4[q] = h2row[q];
        const float* hv = (const float*)hv4;
        #pragma unroll
        for (int hh = 0; hh < EMB; ++hh) {
            const float4* wrow = (const float4*)&w2s[(rq * EMB + hh) * NC + c0];
            float hvv = hv[hh];
            #pragma unroll
            for (int q5 = 0; q5 < 5; ++q5) {
                float4 wv = wrow[q5];
                acc[q5 * 4 + 0] = fmaf(wv.x, hvv, acc[q5 * 4 + 0]);
                acc[q5 * 4 + 1] = fmaf(wv.y, hvv, acc[q5 * 4 + 1]);
                acc[q5 * 4 + 2] = fmaf(wv.z, hvv, acc[q5 * 4 + 2]);
                acc[q5 * 4 + 3] = fmaf(wv.w, hvv, acc[q5 * 4 + 3]);
            }
        }
    }
    float4* op = (float4*)&out[node * NC + c0];
    #pragma unroll
    for (int q5 = 0; q5 < 5; ++q5)
        op[q5] = make_float4(acc[q5 * 4], acc[q5 * 4 + 1],
                             acc[q5 * 4 + 2], acc[q5 * 4 + 3]);
}

// ---------------------------------------------------------------------------
extern "C" void kernel_launch(void* const* d_in, const int* in_sizes, int n_in,
                              void* d_out, int out_size, void* d_ws, size_t ws_size,
                              hipStream_t stream) {
    const float* rel_emb = (const float*)d_in[0];
    const float* w1      = (const float*)d_in[1];
    const float* w2      = (const float*)d_in[2];
    const float* b1      = (const float*)d_in[3];
    const float* b2      = (const float*)d_in[4];
    const int*   rm_rows = (const int*)d_in[5];
    const int*   rm_cols = (const int*)d_in[6];
    const float* rm_vals = (const float*)d_in[7];
    const int*   h_rows  = (const int*)d_in[8];   // [0:nt] = s_u (sorted!)
    const int*   v_cols  = (const int*)d_in[11];  // [0:nt] = o_u

    const int nm = in_sizes[5];
    const int ne = in_sizes[8];
    const int nt = ne / RP;
    const int n  = in_sizes[1] / (RP * EMB);

    const int B = 256;
    const int nblk_h2 = (n * 16 + B - 1) / B;
    const int nblk_sc = (n + 1023) / 1024;

    char* w = (char*)d_ws;
    // --- zeroed region (small) ---
    float* colsum = (float*)w;  w += (size_t)n * RP * 4;
    float* rowsum = (float*)w;  w += (size_t)n * RP * 4;
    float* h      = (float*)w;  w += (size_t)n * EMB * 4;
    int* cnt_s    = (int*)w;    w += (size_t)n * 4;
    int* cnt_o    = (int*)w;    w += (size_t)n * 4;
    size_t zero_bytes = (size_t)(w - (char*)d_ws);
    // --- written-before-read region ---
    float* M2     = (float*)w;  w += (size_t)n * 15 * EMB * 4;   // 48 MB
    // lat region (dead after k_h2) overlaid with h2n (used from k_gather on)
    char* latbase = w;
    float* lat_t  = (float*)w;  w += (size_t)nt * RP * 4;
    float* lat_o  = (float*)w;  w += (size_t)nt * RP * 4;
    float* lat0   = (float*)w;  w += (size_t)nt * 4;
    int* su_o     = (int*)w;    w += (size_t)nt * 4;
    size_t lat_bytes = (size_t)(w - latbase);
    size_t h2n_bytes = (size_t)n * RP * EMB * 4;                 // 51 MB
    float* h2n = (float*)latbase;
    w = latbase + (lat_bytes > h2n_bytes ? lat_bytes : h2n_bytes);
    int* offs_s   = (int*)w;    w += (size_t)n * 4;
    int* cur_s    = (int*)w;    w += (size_t)n * 4;
    int* offs_o   = (int*)w;    w += (size_t)n * 4;
    int* cur_o    = (int*)w;    w += (size_t)n * 4;
    float* r0part = (float*)w;  w += (size_t)nblk_h2 * EMB * 4;
    float* g0     = (float*)w;  w += (size_t)EMB * 4;
    int* partials = (int*)w;    w += (size_t)2 * nblk_sc * 4;
    if ((size_t)(w - (char*)d_ws) > ws_size) return;

    hipMemsetAsync(d_ws, 0, zero_bytes, stream);

    k_count<<<dim3((nt + B - 1) / B), dim3(B), 0, stream>>>(
        h_rows, v_cols, cnt_s, cnt_o, nt);
    k_scan_blk<<<dim3(nblk_sc, 2), dim3(B), 0, stream>>>(
        cnt_s, offs_s, cnt_o, offs_o, partials, n, nblk_sc);
    k_scan_top<<<dim3(1), dim3(128), 0, stream>>>(partials, nblk_sc);
    k_scan_add<<<dim3(nblk_sc, 2), dim3(B), 0, stream>>>(
        offs_s, cur_s, offs_o, cur_o, partials, n, nblk_sc);
    k_latents<<<dim3((nm * 16 + B - 1) / B), dim3(B), 0, stream>>>(
        rel_emb, rm_rows, rm_cols, rm_vals, h_rows, v_cols,
        cur_o, lat_t, lat_o, lat0, su_o, nm);
    k_r0<<<dim3(64), dim3(B), 0, stream>>>(lat0, rowsum, colsum, nt);
    k_latsum<<<dim3((n * 16 + B - 1) / B), dim3(B), 0, stream>>>(
        lat_o, offs_o, cnt_o, colsum, n);
    k_h_acc<<<dim3((n * 16 + B - 1) / B), dim3(B), 0, stream>>>(
        lat_o, offs_o, cnt_o, su_o, colsum, w1, h, n);
    k_h2<<<dim3(nblk_h2), dim3(B), 0, stream>>>(
        lat_t, offs_s, cnt_s, v_cols, rowsum, h, b1, M2, r0part, n);
    k_h2r0<<<dim3(1), dim3(1024), 0, stream>>>(r0part, g0, nblk_h2);
    k_gather<<<dim3((n * RP * EMB + B - 1) / B), dim3(B), 0, stream>>>(
        M2, g0, rowsum, h2n, n);
    k_out<<<dim3((n * 2 + B - 1) / B), dim3(B), 0, stream>>>(
        w2, b2, h2n, (float*)d_out, n);
}

// Round 16
// 271.738 us; speedup vs baseline: 1.2699x; 1.0728x over previous
//
#include <hip/hip_runtime.h>

#define RP 16
#define EMB 16
#define NC 40

// Broadcast lane R (0..15, compile-time constant) of each 16-lane DPP row.
#define BCASTF(dst, srci, R) \
    dst = __int_as_float(__builtin_amdgcn_mov_dpp(srci, 0x150 + R, 0xf, 0xf, true));

// ---------------------------------------------------------------------------
// Bucket counts per s and per o.
__global__ void k_count(const int* __restrict__ s_u, const int* __restrict__ o_u,
                        int* __restrict__ cnt_s, int* __restrict__ cnt_o, int nt) {
    int t = blockIdx.x * blockDim.x + threadIdx.x;
    if (t < nt) {
        atomicAdd(&cnt_s[s_u[t]], 1);
        atomicAdd(&cnt_o[o_u[t]], 1);
    }
}

// ---------------------------------------------------------------------------
// 3-phase hierarchical exclusive scan (2 arrays via blockIdx.y).
__global__ void k_scan_blk(const int* __restrict__ cnt_s, int* __restrict__ offs_s,
                           const int* __restrict__ cnt_o, int* __restrict__ offs_o,
                           int* __restrict__ partials, int n, int nblk) {
    const int* in = blockIdx.y ? cnt_o : cnt_s;
    int* out = blockIdx.y ? offs_o : offs_s;
    int tid = threadIdx.x;
    int i0 = blockIdx.x * 1024 + tid * 4;
    int v[4];
    #pragma unroll
    for (int q = 0; q < 4; ++q) {
        int i = i0 + q;
        v[q] = (i < n) ? in[i] : 0;
    }
    int tsum = v[0] + v[1] + v[2] + v[3];
    int lane = tid & 63, wid = tid >> 6;
    int x = tsum;
    #pragma unroll
    for (int d = 1; d < 64; d <<= 1) {
        int u = __shfl_up(x, d, 64);
        if (lane >= d) x += u;
    }
    __shared__ int wsum[4];
    if (lane == 63) wsum[wid] = x;
    __syncthreads();
    int woff = 0;
    for (int wq = 0; wq < wid; ++wq) woff += wsum[wq];
    int run = woff + x - tsum;
    #pragma unroll
    for (int q = 0; q < 4; ++q) {
        int i = i0 + q;
        if (i < n) out[i] = run;
        run += v[q];
    }
    if (tid == 255) partials[blockIdx.y * nblk + blockIdx.x] = run;
}

__global__ void k_scan_top(int* __restrict__ partials, int nblk) {
    int w = threadIdx.x >> 6;
    int lane = threadIdx.x & 63;
    int carry = 0;
    for (int base = 0; base < nblk; base += 64) {
        int idx = base + lane;
        int v = (idx < nblk) ? partials[w * nblk + idx] : 0;
        int x = v;
        #pragma unroll
        for (int d = 1; d < 64; d <<= 1) {
            int u = __shfl_up(x, d, 64);
            if (lane >= d) x += u;
        }
        if (idx < nblk) partials[w * nblk + idx] = carry + x - v;
        carry += __shfl(x, 63, 64);
    }
}

__global__ void k_scan_add(int* __restrict__ offs_s, int* __restrict__ cur_s,
                           int* __restrict__ offs_o, int* __restrict__ cur_o,
                           const int* __restrict__ partials, int n, int nblk) {
    int* out = blockIdx.y ? offs_o : offs_s;
    int* cur = blockIdx.y ? cur_o : cur_s;
    int add = partials[blockIdx.y * nblk + blockIdx.x];
    int i0 = blockIdx.x * 1024 + threadIdx.x * 4;
    #pragma unroll
    for (int q = 0; q < 4; ++q) {
        int i = i0 + q;
        if (i < n) {
            int vv = out[i] + add;
            out[i] = vv;
            cur[i] = vv;
        }
    }
}

// ---------------------------------------------------------------------------
// Fused: segment-sum over sorted rm_rows -> softmax ->
//   lat_t  : t-order (coalesced) == s-bucket order (s_u sorted!)
//   lat_o  : o-bucket order (cursor scatter), with su_o companion
//   lat0   : k=0 column in t-order (for the global r0 total)
__global__ void k_latents(const float* __restrict__ rel_emb,
                          const int* __restrict__ rows,
                          const int* __restrict__ cols,
                          const float* __restrict__ vals,
                          const int* __restrict__ s_u,
                          const int* __restrict__ o_u,
                          int* __restrict__ cur_o,
                          float* __restrict__ lat_t, float* __restrict__ lat_o,
                          float* __restrict__ lat0, int* __restrict__ su_o,
                          int nm) {
    int i = blockIdx.x * blockDim.x + threadIdx.x;
    int e = i >> 4, k = i & 15;
    if (e >= nm) return;
    int row = rows[e];
    if (e > 0 && rows[e - 1] == row) return;          // not a row leader
    float acc = vals[e] * rel_emb[cols[e] * RP + k];
    while (e + 1 < nm && rows[e + 1] == row) {
        ++e;
        acc += vals[e] * rel_emb[cols[e] * RP + k];
    }
    float m = acc;
    #pragma unroll
    for (int d = 1; d < 16; d <<= 1) m = fmaxf(m, __shfl_xor(m, d, 16));
    float v = expf(acc - m);
    float s = v;
    #pragma unroll
    for (int d = 1; d < 16; d <<= 1) s += __shfl_xor(s, d, 16);
    v = v / s;
    lat_t[(size_t)row * RP + k] = v;                  // coalesced
    int po = 0;
    if (k == 0) {
        int ou = o_u[row];
        po = atomicAdd(&cur_o[ou], 1);
        su_o[po] = s_u[row];
        lat0[row] = v;
    }
    po = __shfl(po, 0, 16);
    lat_o[(size_t)po * RP + k] = v;                   // scattered 64B row
}

// ---------------------------------------------------------------------------
// Global r0 total G = sum_t lat[t,0] -> rowsum[0], colsum[0].
__global__ void k_r0(const float* __restrict__ lat0,
                     float* __restrict__ rowsum, float* __restrict__ colsum,
                     int nt) {
    float acc = 0.f;
    for (int t = blockIdx.x * blockDim.x + threadIdx.x; t < nt;
         t += gridDim.x * blockDim.x)
        acc += lat0[t];
    #pragma unroll
    for (int d = 32; d; d >>= 1) acc += __shfl_down(acc, d, 64);
    __shared__ float sm[4];
    int lane = threadIdx.x & 63, wid = threadIdx.x >> 6;
    if (lane == 0) sm[wid] = acc;
    __syncthreads();
    if (threadIdx.x == 0) {
        float tot = sm[0] + sm[1] + sm[2] + sm[3];
        atomicAdd(&rowsum[0], tot);
        atomicAdd(&colsum[0], tot);
    }
}

// ---------------------------------------------------------------------------
// colsum: per-o latent sums (linear bucket reads); aliased (v*k) atomics.
__global__ void k_latsum(const float* __restrict__ lat_o,
                         const int* __restrict__ offs_o,
                         const int* __restrict__ cnt_o,
                         float* __restrict__ colsum, int n) {
    int i = blockIdx.x * blockDim.x + threadIdx.x;
    int v = i >> 4, k = i & 15;
    if (v >= n) return;
    int beg = offs_o[v], d = cnt_o[v];
    if (d == 0) return;
    float ls = 0.f;
    int j = 0;
    for (; j + 4 <= d; j += 4) {
        float a0 = lat_o[(size_t)(beg + j + 0) * RP + k];
        float a1 = lat_o[(size_t)(beg + j + 1) * RP + k];
        float a2 = lat_o[(size_t)(beg + j + 2) * RP + k];
        float a3 = lat_o[(size_t)(beg + j + 3) * RP + k];
        ls += (a0 + a1) + (a2 + a3);
    }
    for (; j < d; ++j) ls += lat_o[(size_t)(beg + j) * RP + k];
    if (k >= 1) atomicAdd(&colsum[(size_t)v * k], ls);
}

// ---------------------------------------------------------------------------
// Stage 4: per-o accumulation into raw h. Chunk-16 preload + DPP FMA.
__global__ void k_h_acc(const float* __restrict__ lat_o,
                        const int* __restrict__ offs_o,
                        const int* __restrict__ cnt_o,
                        const int* __restrict__ su_o,
                        const float* __restrict__ colsum,
                        const float* __restrict__ w1,
                        float* __restrict__ h, int n) {
    int i = blockIdx.x * blockDim.x + threadIdx.x;
    int o = i >> 4, k = i & 15;
    if (o >= n) return;
    int d = cnt_o[o];
    if (d == 0) return;
    int beg = offs_o[o];
    float W[RP];
    #pragma unroll
    for (int r = 0; r < RP; ++r)
        W[r] = w1[(size_t)(o * r) * EMB + k];
    float rcp_cs = 1.f / colsum[(size_t)o * k];
    for (int j0 = 0; j0 < d; j0 += 16) {
        int su16 = su_o[beg + min(j0 + k, d - 1)];    // lane k: entry j0+k
        float la[16];
        #pragma unroll
        for (int e = 0; e < 16; ++e)
            la[e] = lat_o[(size_t)(beg + min(j0 + e, d - 1)) * RP + k];
        #pragma unroll
        for (int e = 0; e < 16; ++e) {
            if (j0 + e >= d) break;                   // uniform across group
            float ln = la[e] * rcp_cs;
            int ln_i = __float_as_int(ln);
            float acc = 0.f, b;
            #define HACC_STEP(R) BCASTF(b, ln_i, R); acc = fmaf(b, W[R], acc);
            HACC_STEP(0)  HACC_STEP(1)  HACC_STEP(2)  HACC_STEP(3)
            HACC_STEP(4)  HACC_STEP(5)  HACC_STEP(6)  HACC_STEP(7)
            HACC_STEP(8)  HACC_STEP(9)  HACC_STEP(10) HACC_STEP(11)
            HACC_STEP(12) HACC_STEP(13) HACC_STEP(14) HACC_STEP(15)
            #undef HACC_STEP
            int s = __shfl(su16, e, 16);
            atomicAdd(&h[s * EMB + k], acc);
        }
    }
}

// ---------------------------------------------------------------------------
// Stage 5+6: per-s outer-product. M[r] (r>=1) written PLAIN (collision-free
// [s][r-1][k] layout — s*r is injective for fixed r); collisions summed by
// k_gather. rowsum accumulated here (atomic, aliased s*k). r==0 -> g0.
__global__ void k_h2(const float* __restrict__ lat_t,
                     const int* __restrict__ offs_s,
                     const int* __restrict__ cnt_s,
                     const int* __restrict__ o_u,
                     float* __restrict__ rowsum,
                     const float* __restrict__ h,
                     const float* __restrict__ bias1,
                     float* __restrict__ M2,
                     float* __restrict__ r0part, int n) {
    __shared__ float r0acc[EMB];
    if (threadIdx.x < EMB) r0acc[threadIdx.x] = 0.f;
    __syncthreads();
    int i = blockIdx.x * blockDim.x + threadIdx.x;
    int s = i >> 4, k = i & 15;
    float b1k = bias1[k];
    float M[RP];
    #pragma unroll
    for (int r = 0; r < RP; ++r) M[r] = 0.f;
    float rs_acc = 0.f;
    int d = 0;
    if (s < n) {
        int beg = offs_s[s];
        d = cnt_s[s];
        for (int j0 = 0; j0 < d; j0 += 16) {
            int o16 = o_u[beg + min(j0 + k, d - 1)];  // lane k: entry j0+k
            float hv[16], la[16];
            #pragma unroll
            for (int e = 0; e < 16; ++e) {
                int oe = __shfl(o16, e, 16);
                hv[e] = h[(size_t)oe * EMB + k];      // coalesced 64B row
                la[e] = lat_t[(size_t)(beg + min(j0 + e, d - 1)) * RP + k];
            }
            #pragma unroll
            for (int e = 0; e < 16; ++e) {
                if (j0 + e >= d) break;               // uniform across group
                float hvr = fmaxf(hv[e] + b1k, 0.f);
                rs_acc += la[e];
                int lat_i = __float_as_int(la[e]);
                float b;
                #define H2_STEP(R) BCASTF(b, lat_i, R); M[R] = fmaf(b, hvr, M[R]);
                H2_STEP(0)  H2_STEP(1)  H2_STEP(2)  H2_STEP(3)
                H2_STEP(4)  H2_STEP(5)  H2_STEP(6)  H2_STEP(7)
                H2_STEP(8)  H2_STEP(9)  H2_STEP(10) H2_STEP(11)
                H2_STEP(12) H2_STEP(13) H2_STEP(14) H2_STEP(15)
                #undef H2_STEP
            }
        }
    }
    if (s < n) {
        if (d > 0) {
            if (k >= 1) atomicAdd(&rowsum[(size_t)s * k], rs_acc);
            atomicAdd(&r0acc[k], M[0]);
        }
        float* dst = &M2[(size_t)s * 15 * EMB + k];   // zeros when d == 0
        #pragma unroll
        for (int r = 1; r < RP; ++r)
            dst[(size_t)(r - 1) * EMB] = M[r];
    }
    __syncthreads();
    if (threadIdx.x < EMB)
        r0part[(size_t)blockIdx.x * EMB + threadIdx.x] = r0acc[threadIdx.x];
}

// Reduce r0part (nblk x 16) into g0[0:16]. One block of 1024.
__global__ void k_h2r0(const float* __restrict__ r0part,
                       float* __restrict__ g0, int nblk) {
    __shared__ float red[1024];
    int k = threadIdx.x & 15, j0 = threadIdx.x >> 4;   // j0 in [0,64)
    float acc = 0.f;
    for (int j = j0; j < nblk; j += 64)
        acc += r0part[(size_t)j * EMB + k];
    red[j0 * 16 + k] = acc;
    __syncthreads();
    #pragma unroll
    for (int st = 32; st >= 1; st >>= 1) {
        if (j0 < st) red[j0 * 16 + k] += red[(j0 + st) * 16 + k];
        __syncthreads();
    }
    if (threadIdx.x < 16) g0[threadIdx.x] = red[threadIdx.x];
}

// ---------------------------------------------------------------------------
// Collision gather: 16-lane group per flat row m. Lane-parallel divisor
// test (lane k tests r = k, one runtime div) -> ballot -> short uniform
// loop over the ~3.3 hits, each one coalesced M2 row read. No LDS/atomics.
__global__ void k_gather(const float* __restrict__ M2,
                         const float* __restrict__ g0,
                         const float* __restrict__ rowsum,
                         float* __restrict__ h2n, int n) {
    int gi = blockIdx.x * blockDim.x + threadIdx.x;
    int m = gi >> 4, k = gi & 15;
    if (m >= n * RP) return;
    unsigned q = 0;
    bool hit = false;
    if (k >= 1) {
        q = (unsigned)m / (unsigned)k;                // runtime div, once
        hit = (q * (unsigned)k == (unsigned)m) && (q < (unsigned)n);
    }
    unsigned long long bal = __ballot(hit);
    int base = threadIdx.x & 48;                      // this group's 16 lanes
    unsigned mask = (unsigned)((bal >> base) & 0xFFFFull);
    float hv = (m == 0) ? g0[k] : 0.f;
    int qi = (int)q;
    while (mask) {                                    // group-uniform loop
        int r = __ffs(mask) - 1;
        mask &= mask - 1;
        int s = __shfl(qi, r, 16);                    // lane r holds m/r
        hv += M2[((size_t)s * 15 + (r - 1)) * EMB + k];
    }
    float rs = rowsum[m];
    float rcp = (rs != 0.f) ? 1.f / rs : 0.f;
    h2n[(size_t)m * EMB + k] = hv * rcp;
}

// ---------------------------------------------------------------------------
// Stage 7 (round-8 shape): w2 staged in LDS; thread = (node, 20-col half);
// dense pre-normalized h2n rows, float4 everywhere.
#define CB2 20
__global__ void k_out(const float* __restrict__ w2,
                      const float* __restrict__ bias2,
                      const float* __restrict__ h2n,
                      float* __restrict__ out, int n) {
    __shared__ float w2s[RP * EMB * NC];          // 10240 floats = 40 KB
    for (int i = threadIdx.x; i < RP * EMB * NC; i += 256)
        w2s[i] = w2[i];
    __syncthreads();
    int gi = blockIdx.x * blockDim.x + threadIdx.x;
    int node = gi >> 1;
    int c0 = (gi & 1) * CB2;
    if (node >= n) return;
    float acc[CB2];
    #pragma unroll
    for (int c = 0; c < CB2; ++c) acc[c] = bias2[c0 + c];
    for (int rq = 0; rq < RP; ++rq) {
        const float4* h2row = (const float4*)&h2n[((size_t)rq * n + node) * EMB];
        float4 hv4[4];
        #pragma unroll
        for (int q = 0; q < 4; ++q) hv4[q] = h2row[q];
        const float* hv = (const float*)hv4;
        #pragma unroll
        for (int hh = 0; hh < EMB; ++hh) {
            const float4* wrow = (const float4*)&w2s[(rq * EMB + hh) * NC + c0];
            float hvv = hv[hh];
            #pragma unroll
            for (int q5 = 0; q5 < 5; ++q5) {
                float4 wv = wrow[q5];
                acc[q5 * 4 + 0] = fmaf(wv.x, hvv, acc[q5 * 4 + 0]);
                acc[q5 * 4 + 1] = fmaf(wv.y, hvv, acc[q5 * 4 + 1]);
                acc[q5 * 4 + 2] = fmaf(wv.z, hvv, acc[q5 * 4 + 2]);
                acc[q5 * 4 + 3] = fmaf(wv.w, hvv, acc[q5 * 4 + 3]);
            }
        }
    }
    float4* op = (float4*)&out[node * NC + c0];
    #pragma unroll
    for (int q5 = 0; q5 < 5; ++q5)
        op[q5] = make_float4(acc[q5 * 4], acc[q5 * 4 + 1],
                             acc[q5 * 4 + 2], acc[q5 * 4 + 3]);
}

// ---------------------------------------------------------------------------
extern "C" void kernel_launch(void* const* d_in, const int* in_sizes, int n_in,
                              void* d_out, int out_size, void* d_ws, size_t ws_size,
                              hipStream_t stream) {
    const float* rel_emb = (const float*)d_in[0];
    const float* w1      = (const float*)d_in[1];
    const float* w2      = (const float*)d_in[2];
    const float* b1      = (const float*)d_in[3];
    const float* b2      = (const float*)d_in[4];
    const int*   rm_rows = (const int*)d_in[5];
    const int*   rm_cols = (const int*)d_in[6];
    const float* rm_vals = (const float*)d_in[7];
    const int*   h_rows  = (const int*)d_in[8];   // [0:nt] = s_u (sorted!)
    const int*   v_cols  = (const int*)d_in[11];  // [0:nt] = o_u

    const int nm = in_sizes[5];
    const int ne = in_sizes[8];
    const int nt = ne / RP;
    const int n  = in_sizes[1] / (RP * EMB);

    const int B = 256;
    const int nblk_h2 = (n * 16 + B - 1) / B;
    const int nblk_sc = (n + 1023) / 1024;

    char* w = (char*)d_ws;
    // --- zeroed region (small) ---
    float* colsum = (float*)w;  w += (size_t)n * RP * 4;
    float* rowsum = (float*)w;  w += (size_t)n * RP * 4;
    float* h      = (float*)w;  w += (size_t)n * EMB * 4;
    int* cnt_s    = (int*)w;    w += (size_t)n * 4;
    int* cnt_o    = (int*)w;    w += (size_t)n * 4;
    size_t zero_bytes = (size_t)(w - (char*)d_ws);
    // --- written-before-read region ---
    float* M2     = (float*)w;  w += (size_t)n * 15 * EMB * 4;   // 48 MB
    // lat region (dead after k_h2) overlaid with h2n (used from k_gather on)
    char* latbase = w;
    float* lat_t  = (float*)w;  w += (size_t)nt * RP * 4;
    float* lat_o  = (float*)w;  w += (size_t)nt * RP * 4;
    float* lat0   = (float*)w;  w += (size_t)nt * 4;
    int* su_o     = (int*)w;    w += (size_t)nt * 4;
    size_t lat_bytes = (size_t)(w - latbase);
    size_t h2n_bytes = (size_t)n * RP * EMB * 4;                 // 51 MB
    float* h2n = (float*)latbase;
    w = latbase + (lat_bytes > h2n_bytes ? lat_bytes : h2n_bytes);
    int* offs_s   = (int*)w;    w += (size_t)n * 4;
    int* cur_s    = (int*)w;    w += (size_t)n * 4;
    int* offs_o   = (int*)w;    w += (size_t)n * 4;
    int* cur_o    = (int*)w;    w += (size_t)n * 4;
    float* r0part = (float*)w;  w += (size_t)nblk_h2 * EMB * 4;
    float* g0     = (float*)w;  w += (size_t)EMB * 4;
    int* partials = (int*)w;    w += (size_t)2 * nblk_sc * 4;
    if ((size_t)(w - (char*)d_ws) > ws_size) return;

    hipMemsetAsync(d_ws, 0, zero_bytes, stream);

    k_count<<<dim3((nt + B - 1) / B), dim3(B), 0, stream>>>(
        h_rows, v_cols, cnt_s, cnt_o, nt);
    k_scan_blk<<<dim3(nblk_sc, 2), dim3(B), 0, stream>>>(
        cnt_s, offs_s, cnt_o, offs_o, partials, n, nblk_sc);
    k_scan_top<<<dim3(1), dim3(128), 0, stream>>>(partials, nblk_sc);
    k_scan_add<<<dim3(nblk_sc, 2), dim3(B), 0, stream>>>(
        offs_s, cur_s, offs_o, cur_o, partials, n, nblk_sc);
    k_latents<<<dim3((nm * 16 + B - 1) / B), dim3(B), 0, stream>>>(
        rel_emb, rm_rows, rm_cols, rm_vals, h_rows, v_cols,
        cur_o, lat_t, lat_o, lat0, su_o, nm);
    k_r0<<<dim3(64), dim3(B), 0, stream>>>(lat0, rowsum, colsum, nt);
    k_latsum<<<dim3((n * 16 + B - 1) / B), dim3(B), 0, stream>>>(
        lat_o, offs_o, cnt_o, colsum, n);
    k_h_acc<<<dim3((n * 16 + B - 1) / B), dim3(B), 0, stream>>>(
        lat_o, offs_o, cnt_o, su_o, colsum, w1, h, n);
    k_h2<<<dim3(nblk_h2), dim3(B), 0, stream>>>(
        lat_t, offs_s, cnt_s, v_cols, rowsum, h, b1, M2, r0part, n);
    k_h2r0<<<dim3(1), dim3(1024), 0, stream>>>(r0part, g0, nblk_h2);
    k_gather<<<dim3((n * RP * EMB + B - 1) / B), dim3(B), 0, stream>>>(
        M2, g0, rowsum, h2n, n);
    k_out<<<dim3((n * 2 + B - 1) / B), dim3(B), 0, stream>>>(
        w2, b2, h2n, (float*)d_out, n);
}